// Round 10
// baseline (193.286 us; speedup 1.0000x reference)
//
#include <hip/hip_runtime.h>
#include <math.h>

// Dims: N=2, T=2048, DM=1024, H=8, E=4, L=32, DK=DV=64
// Numerics: scan multiplier (1-sum_h G) ~ -1.4 => rec ~1e9, logits ~1e8
// (softmax==argmax). Logit-path inputs use split-bf16 (hi+lo, ~2^-17):
// argmax-brittle. Post-softmax paths (P, V at attn, Y, wO) are plain bf16.
// R9 lesson: non-uniform per-block work (V-tiles 1-term) regressed — VGPR
// 96->120 and no makespan gain. Keep all blocks uniform.

typedef __attribute__((ext_vector_type(8))) short bf16x8;
typedef __attribute__((ext_vector_type(4))) float f32x4;

static __device__ __forceinline__ unsigned short f2bf(float f) {
  unsigned u = __float_as_uint(f);
  u += 0x7fffu + ((u >> 16) & 1u);   // RNE
  return (unsigned short)(u >> 16);
}
static __device__ __forceinline__ float bf2f(unsigned short h) {
  return __uint_as_float(((unsigned)h) << 16);
}
static __device__ __forceinline__ unsigned packbf(float f) {
  unsigned short h = f2bf(f);
  unsigned short l = f2bf(f - bf2f(h));
  return ((unsigned)h << 16) | (unsigned)l;
}
static __device__ __forceinline__ float unpackbf(unsigned u) {
  return __uint_as_float(u & 0xffff0000u) + __uint_as_float(u << 16);
}

#define GLDS(gp, lp) \
  __builtin_amdgcn_global_load_lds((const __attribute__((address_space(1))) void*)(gp), \
                                   (__attribute__((address_space(3))) void*)(lp), 16, 0, 0)

// ------- converts: X,W -> hi/lo planes; wO -> transposed hi plane (fused) ---
__global__ __launch_bounds__(256) void cvt_all(
    const float* __restrict__ X,
    const float* __restrict__ wK, const float* __restrict__ wV,
    const float* __restrict__ wQ, const float* __restrict__ wG,
    const float* __restrict__ wO,
    unsigned short* __restrict__ Xh, unsigned short* __restrict__ Xl,
    unsigned short* __restrict__ Wh, unsigned short* __restrict__ Wl,
    unsigned short* __restrict__ wOth)
{
  __shared__ float tile[32][33];
  const int b   = blockIdx.x;
  const int tid = threadIdx.x;
  if (b < 5760) {
    const int g = b * 256 + tid;
    const float* src;
    unsigned short *dh, *dl;
    int idx;
    if (g < 1048576) {              // X: 4,194,304 floats
      idx = g * 4;
      src = X + idx;
      dh = Xh + idx; dl = Xl + idx;
    } else {                        // W: 1664 rows x 1024
      idx = (g - 1048576) * 4;
      const int row = idx >> 10;
      const int col = idx & 1023;
      const float* s = nullptr;
      if (row < 512)       s = wK + (size_t)row * 1024;
      else if (row < 1024) s = wV + (size_t)(row - 512) * 1024;
      else if (row < 1536) s = wQ + (size_t)(row - 1024) * 1024;
      else if (row < 1568) s = wG + (size_t)(row - 1536) * 1024;
      src = s ? s + col : nullptr;
      dh = Wh + idx; dl = Wl + idx;
    }
    float4 v = make_float4(0.f, 0.f, 0.f, 0.f);
    if (src) v = *(const float4*)src;
    ushort4 h, l;
    h.x = f2bf(v.x); l.x = f2bf(v.x - bf2f(h.x));
    h.y = f2bf(v.y); l.y = f2bf(v.y - bf2f(h.y));
    h.z = f2bf(v.z); l.z = f2bf(v.z - bf2f(h.z));
    h.w = f2bf(v.w); l.w = f2bf(v.w - bf2f(h.w));
    *(ushort4*)dh = h;
    *(ushort4*)dl = l;
    return;
  }
  // wOt: wOth[n][k] = bf16(wO[k][n]); 512 blocks of 32x32 tiles
  const int b2 = b - 5760;
  const int n0 = (b2 & 31) * 32;
  const int k0 = (b2 >> 5) * 32;
  const int tx = tid & 31, ty = tid >> 5;
#pragma unroll
  for (int r = 0; r < 4; ++r)
    tile[ty * 4 + r][tx] = wO[(size_t)(k0 + ty * 4 + r) * 1024 + n0 + tx];
  __syncthreads();
#pragma unroll
  for (int r = 0; r < 4; ++r)
    wOth[(size_t)(n0 + ty * 4 + r) * 512 + k0 + tx] = f2bf(tile[tx][ty * 4 + r]);
}

// ---------------- K1: fused projection GEMM (split-bf16 MFMA) ----------------
// 128x64 tiles, BK=64, 832 blocks (32x26) for ~13 waves/CU latency hiding.
// LDS 48KB -> 3 blocks/CU co-resident. All blocks uniform 3-term.
__global__ __launch_bounds__(256) void gemm_proj(
    const unsigned short* __restrict__ Xh, const unsigned short* __restrict__ Xl,
    const unsigned short* __restrict__ Wh, const unsigned short* __restrict__ Wl,
    const float* __restrict__ bG,
    float* __restrict__ Kb, float* __restrict__ Vb, float* __restrict__ Qb,
    float* __restrict__ Gb)
{
  __shared__ __align__(16) unsigned short Ash[2 * 128 * 32];
  __shared__ __align__(16) unsigned short Asl[2 * 128 * 32];
  __shared__ __align__(16) unsigned short Bsh[2 * 64 * 32];
  __shared__ __align__(16) unsigned short Bsl[2 * 64 * 32];
  const int tid  = threadIdx.x;
  const int lane = tid & 63;
  const int w    = tid >> 6;
  const int wr   = w >> 1, wc = w & 1;
  const int lm   = lane & 15, lq = lane >> 4;
  const int rb   = blockIdx.x * 128;
  const int cb   = blockIdx.y * 64;
  const int srow = lane >> 2;          // 0..15
  const int skc  = (lane & 3) * 8;     // 0,8,16,24

  f32x4 acc[4][2] = {};
  for (int k0 = 0; k0 < 1024; k0 += 64) {
#pragma unroll
    for (int p = 0; p < 2; ++p) {
#pragma unroll
      for (int c = 0; c < 2; ++c) {     // A: 8 chunks of 16 rows
        const int r0   = (c * 4 + w) * 16;
        const int ldso = (p * 128 + r0) * 32;
        const size_t ga = (size_t)(rb + r0 + srow) * 1024 + k0 + p * 32 + skc;
        GLDS(Xh + ga, Ash + ldso);
        GLDS(Xl + ga, Asl + ldso);
      }
      {                                 // B: 4 chunks of 16 rows
        const int r0   = w * 16;
        const int ldso = (p * 64 + r0) * 32;
        const size_t gb = (size_t)(cb + r0 + srow) * 1024 + k0 + p * 32 + skc;
        GLDS(Wh + gb, Bsh + ldso);
        GLDS(Wl + gb, Bsl + ldso);
      }
    }
    __syncthreads();
#pragma unroll
    for (int ks = 0; ks < 2; ++ks) {
      bf16x8 ah[4], al[4], bh[2], bl[2];
#pragma unroll
      for (int i = 0; i < 4; ++i) {
        const int off = (ks * 128 + wr * 64 + i * 16 + lm) * 32 + lq * 8;
        ah[i] = *(const bf16x8*)(Ash + off);
        al[i] = *(const bf16x8*)(Asl + off);
      }
#pragma unroll
      for (int j = 0; j < 2; ++j) {
        const int off = (ks * 64 + wc * 32 + j * 16 + lm) * 32 + lq * 8;
        bh[j] = *(const bf16x8*)(Bsh + off);
        bl[j] = *(const bf16x8*)(Bsl + off);
      }
#pragma unroll
      for (int i = 0; i < 4; ++i)
#pragma unroll
        for (int j = 0; j < 2; ++j) {
          acc[i][j] = __builtin_amdgcn_mfma_f32_16x16x32_bf16(ah[i], bh[j], acc[i][j], 0, 0, 0);
          acc[i][j] = __builtin_amdgcn_mfma_f32_16x16x32_bf16(ah[i], bl[j], acc[i][j], 0, 0, 0);
          acc[i][j] = __builtin_amdgcn_mfma_f32_16x16x32_bf16(al[i], bh[j], acc[i][j], 0, 0, 0);
        }
    }
    __syncthreads();
  }
#pragma unroll
  for (int i = 0; i < 4; ++i) {
#pragma unroll
    for (int j = 0; j < 2; ++j) {
      const int c = cb + wc * 32 + j * 16 + lm;
      if (c >= 1568) continue;
#pragma unroll
      for (int rr = 0; rr < 4; ++rr) {
        const int m = rb + wr * 64 + i * 16 + lq * 4 + rr;
        const int n = m >> 11, t = m & 2047;
        const float v = acc[i][j][rr];
        if (c < 512) {
          Kb[(size_t)((n * 8 + (c >> 6)) * 2048 + t) * 64 + (c & 63)] = v;
        } else if (c < 1024) {
          const int cc = c - 512;
          Vb[(size_t)((n * 8 + (cc >> 6)) * 2048 + t) * 64 + (cc & 63)] = v;
        } else if (c < 1536) {
          const int cc = c - 1024;
          Qb[(size_t)((n * 8 + (cc >> 6)) * 2048 + t) * 64 + (cc & 63)] = v;
        } else {
          const int cc = c - 1536;  // h*4+e
          const float g = 1.0f / (1.0f + __expf(-(v + bG[cc])));
          Gb[(size_t)(n * 32 + cc) * 2048 + t] = g;
        }
      }
    }
  }
}

// ---------------- S1: gate + combine (e-inner; K/V read once) ----------------
__global__ __launch_bounds__(256) void gate_combine(
    const float* __restrict__ Gb,   // (n, h*4+e, t)
    const float* __restrict__ Kb,   // (n,h,t,d)
    const float* __restrict__ Vb,
    float* __restrict__ Afac,       // (n,e,t)
    unsigned* __restrict__ gK,      // (n,e,t,d) packed
    unsigned* __restrict__ gV)
{
  __shared__ float Gs[16][32];      // [tl][h*4+e]
  const int tid = threadIdx.x;
  const int n   = blockIdx.x >> 7;
  const int t0  = (blockIdx.x & 127) * 16;
  for (int idx = tid; idx < 512; idx += 256) {
    const int he = idx & 31, tl = idx >> 5;
    Gs[tl][he] = Gb[((size_t)n * 32 + he) * 2048 + t0 + tl];
  }
  __syncthreads();
  const int d  = tid & 63;
  const int ts = tid >> 6;          // 0..3
#pragma unroll
  for (int tt = 0; tt < 4; ++tt) {
    const int tl = ts * 4 + tt;
    const int t  = t0 + tl;
    float ak[4] = {}, av[4] = {};
#pragma unroll
    for (int h = 0; h < 8; ++h) {
      const float kk = Kb[(size_t)((n * 8 + h) * 2048 + t) * 64 + d];
      const float vv = Vb[(size_t)((n * 8 + h) * 2048 + t) * 64 + d];
#pragma unroll
      for (int e = 0; e < 4; ++e) {
        const float g = Gs[tl][h * 4 + e];
        ak[e] = fmaf(g, kk, ak[e]);
        av[e] = fmaf(g, vv, av[e]);
      }
    }
#pragma unroll
    for (int e = 0; e < 4; ++e) {
      const size_t o = (size_t)((n * 4 + e) * 2048 + t) * 64 + d;
      gK[o] = packbf(ak[e]);
      gV[o] = packbf(av[e]);
    }
  }
  if (tid < 64) {
    const int e = tid & 3, tl = tid >> 2;
    float gs = 0.f;
#pragma unroll
    for (int h = 0; h < 8; ++h) gs += Gs[tl][h * 4 + e];
    Afac[(size_t)(n * 4 + e) * 2048 + t0 + tl] = 1.0f - gs;
  }
}

// ---------------- S2: lag-32 linear scan (streaming, prefetched) -----------
__global__ __launch_bounds__(64) void scan2(
    const float* __restrict__ Afac,   // (n,e,t)
    const unsigned* __restrict__ gK,  // (n,e,t,d) packed
    const unsigned* __restrict__ gV,
    const float* __restrict__ initK,  // (E,32,64)
    const float* __restrict__ initV,
    unsigned* __restrict__ recK,      // (n,e,2080,64) packed
    unsigned* __restrict__ recV)
{
  const int d  = threadIdx.x;
  const int ne = blockIdx.x;
  const int i  = blockIdx.y;
  const int e  = ne & 3;
  const bool isV = (blockIdx.z != 0);
  const unsigned* src = (isV ? gV : gK) + ((size_t)ne * 2048 + i) * 64 + d;
  const float*   init = isV ? initV : initK;
  unsigned*       rec = isV ? recV : recK;

  float y = init[(size_t)(e * 32 + i) * 64 + d];
  rec[(size_t)(ne * 2080 + i) * 64 + d] = packbf(y);
  const float* Arow = Afac + (size_t)ne * 2048 + i;
  unsigned* dst = rec + ((size_t)ne * 2080 + 32 + i) * 64 + d;

  unsigned u0[8];
  float    a0[8];
#pragma unroll
  for (int k = 0; k < 8; ++k) {
    a0[k] = Arow[k * 32];
    u0[k] = src[(size_t)k * 2048];
  }
  for (int J = 0; J < 64; J += 8) {
    unsigned u1[8];
    float    a1[8];
    if (J + 8 < 64) {
#pragma unroll
      for (int k = 0; k < 8; ++k) {
        a1[k] = Arow[(J + 8 + k) * 32];
        u1[k] = src[(size_t)(J + 8 + k) * 2048];
      }
    }
#pragma unroll
    for (int k = 0; k < 8; ++k) {
      y = fmaf(a0[k], y, unpackbf(u0[k]));
      dst[(size_t)(J + k) * 2048] = packbf(y);
    }
#pragma unroll
    for (int k = 0; k < 8; ++k) { a0[k] = a1[k]; u0[k] = u1[k]; }
  }
}

// ---------------- K3: banded MFMA attention (single-barrier) ----------------
#define TB 16
#define KS_SZ 3456            // 48*72 per e per plane
#define KS_LO 13824           // 4*KS_SZ
#define VT_B  27648
#define VT_SZ 5120            // 64*80 per e (hi only)
#define P_B   48128           // VT_B + 4*VT_SZ
__global__ __launch_bounds__(512) void attn_kernel(
    const float* __restrict__ Qb,       // (n,h,t,64) f32
    const unsigned* __restrict__ recK,  // (n,e,2080,64) packed
    const unsigned* __restrict__ recV,
    unsigned short* __restrict__ Ybh)   // (n*T,512) bf16
{
  __shared__ __align__(16) unsigned short lds[57344];
  const int tid  = threadIdx.x;
  const int lane = tid & 63;
  const int w    = tid >> 6;           // head
  const int lm   = lane & 15, lq = lane >> 4;
  const int n    = blockIdx.x >> 7;
  const int blk  = blockIdx.x & 127;
  // XCD swizzle: xcd = bx%8; give each XCD a contiguous 256-t range
  const int t0   = (((blk & 7) << 4) | (blk >> 3)) * TB;
  const int maxidx = (2078 - t0) * 64 + 63;   // clamp reads to s<=2079

  bf16x8 aqh[2], aql[2];
  {
    const float* qrow = Qb + ((size_t)(n * 8 + w) * 2048 + t0 + lm) * 64 + lq * 8;
#pragma unroll
    for (int ks = 0; ks < 2; ++ks) {
      float4 q0 = *(const float4*)(qrow + ks * 32);
      float4 q1 = *(const float4*)(qrow + ks * 32 + 4);
      float qv[8] = {q0.x, q0.y, q0.z, q0.w, q1.x, q1.y, q1.z, q1.w};
#pragma unroll
      for (int j = 0; j < 8; ++j) {
        unsigned short h = f2bf(qv[j]);
        aqh[ks][j] = (short)h;
        aql[ks][j] = (short)f2bf(qv[j] - bf2f(h));
      }
    }
  }

#pragma unroll
  for (int e = 0; e < 4; ++e) {
    const unsigned* sK = recK + ((size_t)(n * 4 + e) * 2080 + t0 + 1) * 64;
    const unsigned* sV = recV + ((size_t)(n * 4 + e) * 2080 + t0 + 1) * 64;
#pragma unroll
    for (int p = 0; p < 6; ++p) {
      const int idx = tid + p * 512;
      const int ci  = idx <= maxidx ? idx : maxidx;
      const int sl  = idx >> 6, d = idx & 63;
      const unsigned uk = sK[ci];
      const unsigned uv = sV[ci];
      lds[e * KS_SZ + sl * 72 + d]         = (unsigned short)(uk >> 16);
      lds[KS_LO + e * KS_SZ + sl * 72 + d] = (unsigned short)(uk & 0xffffu);
      lds[VT_B + e * VT_SZ + d * 80 + sl]  = (unsigned short)(uv >> 16);
    }
  }
  for (int idx = tid; idx < 2048; idx += 512) {   // zero Vt pad cols 48..63
    const int e = idx >> 9, r = idx & 511;
    const int d = r >> 3, c = r & 7;
    *(unsigned*)(lds + VT_B + e * VT_SZ + d * 80 + 48 + c * 2) = 0u;
  }
  const int PWH = P_B + w * 1152;
  {
    const int r = lane >> 2, c0 = 48 + (lane & 3) * 4;
#pragma unroll
    for (int c = 0; c < 4; ++c) lds[PWH + r * 72 + c0 + c] = 0;
  }
  __syncthreads();   // the ONLY block barrier

  f32x4 S[4][3];
#pragma unroll
  for (int e = 0; e < 4; ++e)
#pragma unroll
    for (int j = 0; j < 3; ++j) {
      f32x4 s = {0.f, 0.f, 0.f, 0.f};
#pragma unroll
      for (int ks = 0; ks < 2; ++ks) {
        const int boff = (j * 16 + lm) * 72 + ks * 32 + lq * 8;
        bf16x8 bh = *(const bf16x8*)(lds + e * KS_SZ + boff);
        bf16x8 bl = *(const bf16x8*)(lds + KS_LO + e * KS_SZ + boff);
        s = __builtin_amdgcn_mfma_f32_16x16x32_bf16(aqh[ks], bh, s, 0, 0, 0);
        s = __builtin_amdgcn_mfma_f32_16x16x32_bf16(aqh[ks], bl, s, 0, 0, 0);
        s = __builtin_amdgcn_mfma_f32_16x16x32_bf16(aql[ks], bh, s, 0, 0, 0);
      }
      S[e][j] = s;
    }

  const float NEG = -3.0e38f;
  float mx[4] = {NEG, NEG, NEG, NEG};
#pragma unroll
  for (int e = 0; e < 4; ++e)
#pragma unroll
    for (int j = 0; j < 3; ++j) {
      const int sl = j * 16 + lm;
#pragma unroll
      for (int rr = 0; rr < 4; ++rr) {
        const int m = lq * 4 + rr;
        const bool valid = ((unsigned)(sl - m) <= 31u);
        const float v = valid ? S[e][j][rr] * 0.125f : NEG;
        S[e][j][rr] = v;
        mx[rr] = fmaxf(mx[rr], v);
      }
    }
#pragma unroll
  for (int rr = 0; rr < 4; ++rr) {
    float m = mx[rr];
    m = fmaxf(m, __shfl_xor(m, 1));
    m = fmaxf(m, __shfl_xor(m, 2));
    m = fmaxf(m, __shfl_xor(m, 4));
    m = fmaxf(m, __shfl_xor(m, 8));
    mx[rr] = m;
  }
  float sm[4] = {0.f, 0.f, 0.f, 0.f};
#pragma unroll
  for (int e = 0; e < 4; ++e)
#pragma unroll
    for (int j = 0; j < 3; ++j)
#pragma unroll
      for (int rr = 0; rr < 4; ++rr) {
        const float p = __expf(S[e][j][rr] - mx[rr]);
        S[e][j][rr] = p;
        sm[rr] += p;
      }
  float inv[4];
#pragma unroll
  for (int rr = 0; rr < 4; ++rr) {
    float s = sm[rr];
    s += __shfl_xor(s, 1);
    s += __shfl_xor(s, 2);
    s += __shfl_xor(s, 4);
    s += __shfl_xor(s, 8);
    inv[rr] = 1.0f / s;
  }

  f32x4 O[4] = {};
#pragma unroll
  for (int e = 0; e < 4; ++e) {
#pragma unroll
    for (int j = 0; j < 3; ++j)
#pragma unroll
      for (int rr = 0; rr < 4; ++rr)
        lds[PWH + (lq * 4 + rr) * 72 + j * 16 + lm] = f2bf(S[e][j][rr] * inv[rr]);
    bf16x8 ah[2];
#pragma unroll
    for (int ks = 0; ks < 2; ++ks)
      ah[ks] = *(const bf16x8*)(lds + PWH + lm * 72 + ks * 32 + lq * 8);
#pragma unroll
    for (int nt = 0; nt < 4; ++nt)
#pragma unroll
      for (int ks = 0; ks < 2; ++ks) {
        const int boff = (nt * 16 + lm) * 80 + ks * 32 + lq * 8;
        bf16x8 vh = *(const bf16x8*)(lds + VT_B + e * VT_SZ + boff);
        O[nt] = __builtin_amdgcn_mfma_f32_16x16x32_bf16(ah[ks], vh, O[nt], 0, 0, 0);
      }
  }

#pragma unroll
  for (int nt = 0; nt < 4; ++nt)
#pragma unroll
    for (int rr = 0; rr < 4; ++rr) {
      const int t = t0 + lq * 4 + rr;
      const size_t oi = ((size_t)(n * 2048 + t)) * 512 + w * 64 + nt * 16 + lm;
      Ybh[oi] = f2bf(O[nt][rr]);
    }
}

// ---------------- K4: output GEMM (plain bf16 MFMA, BK=64) ----------------
__global__ __launch_bounds__(256) void gemm_out(
    const unsigned short* __restrict__ Yh,
    const unsigned short* __restrict__ Wh,
    float* __restrict__ out)
{
  __shared__ __align__(16) unsigned short Ash[2 * 128 * 32];
  __shared__ __align__(16) unsigned short Bsh[2 * 128 * 32];
  const int tid  = threadIdx.x;
  const int lane = tid & 63;
  const int w    = tid >> 6;
  const int wr   = w >> 1, wc = w & 1;
  const int lm   = lane & 15, lq = lane >> 4;
  const int rb   = blockIdx.x * 128;
  const int cb   = blockIdx.y * 128;
  const int srow = lane >> 2;
  const int skc  = (lane & 3) * 8;

  f32x4 acc[4][4] = {};
  for (int k0 = 0; k0 < 512; k0 += 64) {
#pragma unroll
    for (int p = 0; p < 2; ++p)
#pragma unroll
      for (int c = 0; c < 2; ++c) {
        const int r0   = w * 32 + c * 16;
        const int ldso = (p * 128 + r0) * 32;
        GLDS(Yh + (size_t)(rb + r0 + srow) * 512 + k0 + p * 32 + skc, Ash + ldso);
        GLDS(Wh + (size_t)(cb + r0 + srow) * 512 + k0 + p * 32 + skc, Bsh + ldso);
      }
    __syncthreads();
#pragma unroll
    for (int ks = 0; ks < 2; ++ks) {
      bf16x8 ah[4], bh[4];
#pragma unroll
      for (int i = 0; i < 4; ++i)
        ah[i] = *(const bf16x8*)(Ash + (ks * 128 + wr * 64 + i * 16 + lm) * 32 + lq * 8);
#pragma unroll
      for (int j = 0; j < 4; ++j)
        bh[j] = *(const bf16x8*)(Bsh + (ks * 128 + wc * 64 + j * 16 + lm) * 32 + lq * 8);
#pragma unroll
      for (int i = 0; i < 4; ++i)
#pragma unroll
        for (int j = 0; j < 4; ++j)
          acc[i][j] = __builtin_amdgcn_mfma_f32_16x16x32_bf16(ah[i], bh[j], acc[i][j], 0, 0, 0);
    }
    __syncthreads();
  }
#pragma unroll
  for (int i = 0; i < 4; ++i)
#pragma unroll
    for (int j = 0; j < 4; ++j)
#pragma unroll
      for (int rr = 0; rr < 4; ++rr) {
        const int m = rb + wr * 64 + i * 16 + lq * 4 + rr;
        const int c = cb + wc * 64 + j * 16 + lm;
        out[(size_t)m * 1024 + c] = acc[i][j][rr];
      }
}

extern "C" void kernel_launch(void* const* d_in, const int* in_sizes, int n_in,
                              void* d_out, int out_size, void* d_ws, size_t ws_size,
                              hipStream_t stream) {
  const float* X     = (const float*)d_in[0];
  const float* wG    = (const float*)d_in[1];
  const float* bG    = (const float*)d_in[2];
  const float* wK    = (const float*)d_in[3];
  const float* wV    = (const float*)d_in[4];
  const float* wQ    = (const float*)d_in[5];
  const float* wO    = (const float*)d_in[6];
  const float* initK = (const float*)d_in[7];
  const float* initV = (const float*)d_in[8];
  float* out = (float*)d_out;

  // --- workspace layout (heavy lifetime aliasing) ---
  float* ws = (float*)d_ws;
  float* Kb = ws;                    // 2,097,152 f
  float* Vb = Kb + 2097152;          // 2,097,152 f
  float* Qb = Vb + 2097152;          // 2,097,152 f
  float* Gb = Qb + 2097152;          //   131,072 f
  unsigned short* Xh   = (unsigned short*)(Gb + 131072);  // 4,194,304 s
  unsigned short* Xl   = Xh + 4194304;                    // 4,194,304 s
  unsigned short* Wh   = Xl + 4194304;                    // 1,703,936 s
  unsigned short* Wl   = Wh + 1703936;                    // 1,703,936 s
  unsigned short* wOth = Wl + 1703936;                    //   524,288 s
  // aliases (lifetimes don't overlap):
  unsigned* P    = (unsigned*)Xh;       // X planes dead after gemm_proj
  unsigned* recK = P;                   // 1,064,960 u
  unsigned* recV = P + 1064960;         // 1,064,960 u
  unsigned* gK   = P + 2129920;         // 1,048,576 u
  unsigned* gV   = (unsigned*)Wh;       // 1,048,576 u (W planes dead after gemm_proj)
  float*   Afac  = (float*)(gV + 1048576);  // 16,384 f (inside Wh+Wl region)
  unsigned short* Ybh = (unsigned short*)Kb;  // Kb dead after gate_combine

  cvt_all<<<dim3(6272), dim3(256), 0, stream>>>(X, wK, wV, wQ, wG, wO,
                                                Xh, Xl, Wh, Wl, wOth);
  gemm_proj<<<dim3(32, 26), dim3(256), 0, stream>>>(Xh, Xl, Wh, Wl, bG, Kb, Vb, Qb, Gb);
  gate_combine<<<dim3(256), dim3(256), 0, stream>>>(Gb, Kb, Vb, Afac, gK, gV);
  scan2<<<dim3(8, 32, 2), dim3(64), 0, stream>>>(Afac, gK, gV, initK, initV, recK, recV);
  attn_kernel<<<dim3(256), dim3(512), 0, stream>>>(Qb, recK, recV, Ybh);
  gemm_out<<<dim3(32, 8), dim3(256), 0, stream>>>(Ybh, wOth, out);
}

// Round 11
// 178.361 us; speedup vs baseline: 1.0837x; 1.0837x over previous
//
#include <hip/hip_runtime.h>
#include <math.h>

// Dims: N=2, T=2048, DM=1024, H=8, E=4, L=32, DK=DV=64
// Numerics: scan multiplier (1-sum_h G) ~ -1.4 => rec ~1e9, logits ~1e8
// (softmax==argmax). Logit-path inputs use split-bf16 (hi+lo, ~2^-17):
// argmax-brittle. Post-softmax paths (P, V at attn, Y, wO) are plain bf16.
// R9 lesson: non-uniform per-block work regressed (VGPR bloat, no makespan
// gain). R10 lesson: 128x64 tiles regressed (2x A staging, conflicts) —
// 128x128/BK=64 is gemm_proj's plateau (~703 TF exec). Keep it.

typedef __attribute__((ext_vector_type(8))) short bf16x8;
typedef __attribute__((ext_vector_type(4))) float f32x4;

static __device__ __forceinline__ unsigned short f2bf(float f) {
  unsigned u = __float_as_uint(f);
  u += 0x7fffu + ((u >> 16) & 1u);   // RNE
  return (unsigned short)(u >> 16);
}
static __device__ __forceinline__ float bf2f(unsigned short h) {
  return __uint_as_float(((unsigned)h) << 16);
}
static __device__ __forceinline__ unsigned packbf(float f) {
  unsigned short h = f2bf(f);
  unsigned short l = f2bf(f - bf2f(h));
  return ((unsigned)h << 16) | (unsigned)l;
}
static __device__ __forceinline__ float unpackbf(unsigned u) {
  return __uint_as_float(u & 0xffff0000u) + __uint_as_float(u << 16);
}

#define GLDS(gp, lp) \
  __builtin_amdgcn_global_load_lds((const __attribute__((address_space(1))) void*)(gp), \
                                   (__attribute__((address_space(3))) void*)(lp), 16, 0, 0)

// ------- converts: X,W -> hi/lo planes; wO -> transposed hi plane (fused) ---
__global__ __launch_bounds__(256) void cvt_all(
    const float* __restrict__ X,
    const float* __restrict__ wK, const float* __restrict__ wV,
    const float* __restrict__ wQ, const float* __restrict__ wG,
    const float* __restrict__ wO,
    unsigned short* __restrict__ Xh, unsigned short* __restrict__ Xl,
    unsigned short* __restrict__ Wh, unsigned short* __restrict__ Wl,
    unsigned short* __restrict__ wOth)
{
  __shared__ float tile[32][33];
  const int b   = blockIdx.x;
  const int tid = threadIdx.x;
  if (b < 5760) {
    const int g = b * 256 + tid;
    const float* src;
    unsigned short *dh, *dl;
    int idx;
    if (g < 1048576) {              // X: 4,194,304 floats
      idx = g * 4;
      src = X + idx;
      dh = Xh + idx; dl = Xl + idx;
    } else {                        // W: 1664 rows x 1024
      idx = (g - 1048576) * 4;
      const int row = idx >> 10;
      const int col = idx & 1023;
      const float* s = nullptr;
      if (row < 512)       s = wK + (size_t)row * 1024;
      else if (row < 1024) s = wV + (size_t)(row - 512) * 1024;
      else if (row < 1536) s = wQ + (size_t)(row - 1024) * 1024;
      else if (row < 1568) s = wG + (size_t)(row - 1536) * 1024;
      src = s ? s + col : nullptr;
      dh = Wh + idx; dl = Wl + idx;
    }
    float4 v = make_float4(0.f, 0.f, 0.f, 0.f);
    if (src) v = *(const float4*)src;
    ushort4 h, l;
    h.x = f2bf(v.x); l.x = f2bf(v.x - bf2f(h.x));
    h.y = f2bf(v.y); l.y = f2bf(v.y - bf2f(h.y));
    h.z = f2bf(v.z); l.z = f2bf(v.z - bf2f(h.z));
    h.w = f2bf(v.w); l.w = f2bf(v.w - bf2f(h.w));
    *(ushort4*)dh = h;
    *(ushort4*)dl = l;
    return;
  }
  // wOt: wOth[n][k] = bf16(wO[k][n]); 512 blocks of 32x32 tiles
  const int b2 = b - 5760;
  const int n0 = (b2 & 31) * 32;
  const int k0 = (b2 >> 5) * 32;
  const int tx = tid & 31, ty = tid >> 5;
#pragma unroll
  for (int r = 0; r < 4; ++r)
    tile[ty * 4 + r][tx] = wO[(size_t)(k0 + ty * 4 + r) * 1024 + n0 + tx];
  __syncthreads();
#pragma unroll
  for (int r = 0; r < 4; ++r)
    wOth[(size_t)(n0 + ty * 4 + r) * 512 + k0 + tx] = f2bf(tile[tx][ty * 4 + r]);
}

// ---------------- K1: fused projection GEMM (split-bf16 MFMA, BK=64) --------
// 128x128 tiles (R8 config — the measured plateau). Uniform 3-term.
__global__ __launch_bounds__(256) void gemm_proj(
    const unsigned short* __restrict__ Xh, const unsigned short* __restrict__ Xl,
    const unsigned short* __restrict__ Wh, const unsigned short* __restrict__ Wl,
    const float* __restrict__ bG,
    float* __restrict__ Kb, float* __restrict__ Vb, float* __restrict__ Qb,
    float* __restrict__ Gb)
{
  __shared__ __align__(16) unsigned short Ash[2 * 128 * 32];
  __shared__ __align__(16) unsigned short Asl[2 * 128 * 32];
  __shared__ __align__(16) unsigned short Bsh[2 * 128 * 32];
  __shared__ __align__(16) unsigned short Bsl[2 * 128 * 32];
  const int tid  = threadIdx.x;
  const int lane = tid & 63;
  const int w    = tid >> 6;
  const int wr   = w >> 1, wc = w & 1;
  const int lm   = lane & 15, lq = lane >> 4;
  const int rb   = blockIdx.x * 128;
  const int cb   = blockIdx.y * 128;
  const int srow = lane >> 2;
  const int skc  = (lane & 3) * 8;

  f32x4 acc[4][4] = {};
  for (int k0 = 0; k0 < 1024; k0 += 64) {
#pragma unroll
    for (int p = 0; p < 2; ++p)
#pragma unroll
      for (int c = 0; c < 2; ++c) {
        const int r0   = w * 32 + c * 16;
        const int ldso = (p * 128 + r0) * 32;
        const size_t ga = (size_t)(rb + r0 + srow) * 1024 + k0 + p * 32 + skc;
        const size_t gb = (size_t)(cb + r0 + srow) * 1024 + k0 + p * 32 + skc;
        GLDS(Xh + ga, Ash + ldso);
        GLDS(Xl + ga, Asl + ldso);
        GLDS(Wh + gb, Bsh + ldso);
        GLDS(Wl + gb, Bsl + ldso);
      }
    __syncthreads();
#pragma unroll
    for (int ks = 0; ks < 2; ++ks) {
      bf16x8 ah[4], al[4], bh[4], bl[4];
#pragma unroll
      for (int i = 0; i < 4; ++i) {
        const int off = (ks * 128 + wr * 64 + i * 16 + lm) * 32 + lq * 8;
        ah[i] = *(const bf16x8*)(Ash + off);
        al[i] = *(const bf16x8*)(Asl + off);
      }
#pragma unroll
      for (int j = 0; j < 4; ++j) {
        const int off = (ks * 128 + wc * 64 + j * 16 + lm) * 32 + lq * 8;
        bh[j] = *(const bf16x8*)(Bsh + off);
        bl[j] = *(const bf16x8*)(Bsl + off);
      }
#pragma unroll
      for (int i = 0; i < 4; ++i)
#pragma unroll
        for (int j = 0; j < 4; ++j) {
          acc[i][j] = __builtin_amdgcn_mfma_f32_16x16x32_bf16(ah[i], bh[j], acc[i][j], 0, 0, 0);
          acc[i][j] = __builtin_amdgcn_mfma_f32_16x16x32_bf16(ah[i], bl[j], acc[i][j], 0, 0, 0);
          acc[i][j] = __builtin_amdgcn_mfma_f32_16x16x32_bf16(al[i], bh[j], acc[i][j], 0, 0, 0);
        }
    }
    __syncthreads();
  }
#pragma unroll
  for (int i = 0; i < 4; ++i) {
#pragma unroll
    for (int j = 0; j < 4; ++j) {
      const int c = cb + wc * 64 + j * 16 + lm;
      if (c >= 1568) continue;
#pragma unroll
      for (int rr = 0; rr < 4; ++rr) {
        const int m = rb + wr * 64 + i * 16 + lq * 4 + rr;
        const int n = m >> 11, t = m & 2047;
        const float v = acc[i][j][rr];
        if (c < 512) {
          Kb[(size_t)((n * 8 + (c >> 6)) * 2048 + t) * 64 + (c & 63)] = v;
        } else if (c < 1024) {
          const int cc = c - 512;
          Vb[(size_t)((n * 8 + (cc >> 6)) * 2048 + t) * 64 + (cc & 63)] = v;
        } else if (c < 1536) {
          const int cc = c - 1024;
          Qb[(size_t)((n * 8 + (cc >> 6)) * 2048 + t) * 64 + (cc & 63)] = v;
        } else {
          const int cc = c - 1536;  // h*4+e
          const float g = 1.0f / (1.0f + __expf(-(v + bG[cc])));
          Gb[(size_t)(n * 32 + cc) * 2048 + t] = g;
        }
      }
    }
  }
}

// ---------------- S1: gate + combine (e-inner; K/V read once) ----------------
__global__ __launch_bounds__(256) void gate_combine(
    const float* __restrict__ Gb,   // (n, h*4+e, t)
    const float* __restrict__ Kb,   // (n,h,t,d)
    const float* __restrict__ Vb,
    float* __restrict__ Afac,       // (n,e,t)
    unsigned* __restrict__ gK,      // (n,e,t,d) packed
    unsigned* __restrict__ gV)
{
  __shared__ float Gs[16][32];      // [tl][h*4+e]
  const int tid = threadIdx.x;
  const int n   = blockIdx.x >> 7;
  const int t0  = (blockIdx.x & 127) * 16;
  for (int idx = tid; idx < 512; idx += 256) {
    const int he = idx & 31, tl = idx >> 5;
    Gs[tl][he] = Gb[((size_t)n * 32 + he) * 2048 + t0 + tl];
  }
  __syncthreads();
  const int d  = tid & 63;
  const int ts = tid >> 6;          // 0..3
#pragma unroll
  for (int tt = 0; tt < 4; ++tt) {
    const int tl = ts * 4 + tt;
    const int t  = t0 + tl;
    float ak[4] = {}, av[4] = {};
#pragma unroll
    for (int h = 0; h < 8; ++h) {
      const float kk = Kb[(size_t)((n * 8 + h) * 2048 + t) * 64 + d];
      const float vv = Vb[(size_t)((n * 8 + h) * 2048 + t) * 64 + d];
#pragma unroll
      for (int e = 0; e < 4; ++e) {
        const float g = Gs[tl][h * 4 + e];
        ak[e] = fmaf(g, kk, ak[e]);
        av[e] = fmaf(g, vv, av[e]);
      }
    }
#pragma unroll
    for (int e = 0; e < 4; ++e) {
      const size_t o = (size_t)((n * 4 + e) * 2048 + t) * 64 + d;
      gK[o] = packbf(ak[e]);
      gV[o] = packbf(av[e]);
    }
  }
  if (tid < 64) {
    const int e = tid & 3, tl = tid >> 2;
    float gs = 0.f;
#pragma unroll
    for (int h = 0; h < 8; ++h) gs += Gs[tl][h * 4 + e];
    Afac[(size_t)(n * 4 + e) * 2048 + t0 + tl] = 1.0f - gs;
  }
}

// ---------------- S2: lag-32 linear scan (streaming, prefetched) -----------
__global__ __launch_bounds__(64) void scan2(
    const float* __restrict__ Afac,   // (n,e,t)
    const unsigned* __restrict__ gK,  // (n,e,t,d) packed
    const unsigned* __restrict__ gV,
    const float* __restrict__ initK,  // (E,32,64)
    const float* __restrict__ initV,
    unsigned* __restrict__ recK,      // (n,e,2080,64) packed
    unsigned* __restrict__ recV)
{
  const int d  = threadIdx.x;
  const int ne = blockIdx.x;
  const int i  = blockIdx.y;
  const int e  = ne & 3;
  const bool isV = (blockIdx.z != 0);
  const unsigned* src = (isV ? gV : gK) + ((size_t)ne * 2048 + i) * 64 + d;
  const float*   init = isV ? initV : initK;
  unsigned*       rec = isV ? recV : recK;

  float y = init[(size_t)(e * 32 + i) * 64 + d];
  rec[(size_t)(ne * 2080 + i) * 64 + d] = packbf(y);
  const float* Arow = Afac + (size_t)ne * 2048 + i;
  unsigned* dst = rec + ((size_t)ne * 2080 + 32 + i) * 64 + d;

  unsigned u0[8];
  float    a0[8];
#pragma unroll
  for (int k = 0; k < 8; ++k) {
    a0[k] = Arow[k * 32];
    u0[k] = src[(size_t)k * 2048];
  }
  for (int J = 0; J < 64; J += 8) {
    unsigned u1[8];
    float    a1[8];
    if (J + 8 < 64) {
#pragma unroll
      for (int k = 0; k < 8; ++k) {
        a1[k] = Arow[(J + 8 + k) * 32];
        u1[k] = src[(size_t)(J + 8 + k) * 2048];
      }
    }
#pragma unroll
    for (int k = 0; k < 8; ++k) {
      y = fmaf(a0[k], y, unpackbf(u0[k]));
      dst[(size_t)(J + k) * 2048] = packbf(y);
    }
#pragma unroll
    for (int k = 0; k < 8; ++k) { a0[k] = a1[k]; u0[k] = u1[k]; }
  }
}

// ---------------- K3: banded MFMA attention (compact LDS, 2 blocks/CU) ------
// Block: (n, 16 t-rows), 512 thr = 8 waves (wave=head).
// LDS (shorts): K one expert at a time, hi/lo [48][72] (reused, 7 barriers);
// Vt hi 4e x [64 d][72] (cols 48..63 zeroed); per-wave P hi [16][72].
// Total 34,560 shorts = 69,120 B < 80 KB -> 2 blocks/CU (16 waves/CU).
#define TB 16
#define KS_HI 0               // [48][72] hi, current expert
#define KS_LO 3456            // lo plane
#define VT_B  6912
#define VT_SZ 4608            // 64*72 per e (hi only)
#define P_B   25344           // VT_B + 4*VT_SZ
__global__ __launch_bounds__(512) void attn_kernel(
    const float* __restrict__ Qb,       // (n,h,t,64) f32
    const unsigned* __restrict__ recK,  // (n,e,2080,64) packed
    const unsigned* __restrict__ recV,
    unsigned short* __restrict__ Ybh)   // (n*T,512) bf16
{
  __shared__ __align__(16) unsigned short lds[34560];
  const int tid  = threadIdx.x;
  const int lane = tid & 63;
  const int w    = tid >> 6;           // head
  const int lm   = lane & 15, lq = lane >> 4;
  const int n    = blockIdx.x >> 7;
  const int blk  = blockIdx.x & 127;
  // XCD swizzle: give each XCD a contiguous 256-t range for L2 window reuse
  const int t0   = (((blk & 7) << 4) | (blk >> 3)) * TB;
  const int maxidx = (2078 - t0) * 64 + 63;   // clamp reads to s<=2079

  bf16x8 aqh[2], aql[2];
  {
    const float* qrow = Qb + ((size_t)(n * 8 + w) * 2048 + t0 + lm) * 64 + lq * 8;
#pragma unroll
    for (int ks = 0; ks < 2; ++ks) {
      float4 q0 = *(const float4*)(qrow + ks * 32);
      float4 q1 = *(const float4*)(qrow + ks * 32 + 4);
      float qv[8] = {q0.x, q0.y, q0.z, q0.w, q1.x, q1.y, q1.z, q1.w};
#pragma unroll
      for (int j = 0; j < 8; ++j) {
        unsigned short h = f2bf(qv[j]);
        aqh[ks][j] = (short)h;
        aql[ks][j] = (short)f2bf(qv[j] - bf2f(h));
      }
    }
  }

  // ---- stage V^T hi for all 4 experts (read-only until Phase C) ----
#pragma unroll
  for (int e = 0; e < 4; ++e) {
    const unsigned* sV = recV + ((size_t)(n * 4 + e) * 2080 + t0 + 1) * 64;
#pragma unroll
    for (int p = 0; p < 6; ++p) {
      const int idx = tid + p * 512;
      const int ci  = idx <= maxidx ? idx : maxidx;
      const int sl  = idx >> 6, d = idx & 63;
      lds[VT_B + e * VT_SZ + d * 72 + sl] = (unsigned short)(sV[ci] >> 16);
    }
  }
  // zero Vt pad cols 48..63 (read by PV kstep1 with P=0; must be finite)
  for (int idx = tid; idx < 2048; idx += 512) {   // dword writes
    const int e = idx >> 9, r = idx & 511;
    const int d = r >> 3, c = r & 7;
    *(unsigned*)(lds + VT_B + e * VT_SZ + d * 72 + 48 + c * 2) = 0u;
  }
  // zero this wave's P pad cols 48..63 (own region)
  const int PWH = P_B + w * 1152;
  {
    const int r = lane >> 2, c0 = 48 + (lane & 3) * 4;
#pragma unroll
    for (int c = 0; c < 4; ++c) lds[PWH + r * 72 + c0 + c] = 0;
  }

  // ---- Phase A: scores, K one expert at a time (buffer reuse) ----
  f32x4 S[4][3];
#pragma unroll
  for (int e = 0; e < 4; ++e) {
    __syncthreads();   // e=0: publish Vt/P-pad; e>0: protect K buffer
    {
      const unsigned* sK = recK + ((size_t)(n * 4 + e) * 2080 + t0 + 1) * 64;
#pragma unroll
      for (int p = 0; p < 6; ++p) {
        const int idx = tid + p * 512;
        const int ci  = idx <= maxidx ? idx : maxidx;
        const int sl  = idx >> 6, d = idx & 63;
        const unsigned uk = sK[ci];
        lds[KS_HI + sl * 72 + d] = (unsigned short)(uk >> 16);
        lds[KS_LO + sl * 72 + d] = (unsigned short)(uk & 0xffffu);
      }
    }
    __syncthreads();
#pragma unroll
    for (int j = 0; j < 3; ++j) {
      f32x4 s = {0.f, 0.f, 0.f, 0.f};
#pragma unroll
      for (int ks = 0; ks < 2; ++ks) {
        const int boff = (j * 16 + lm) * 72 + ks * 32 + lq * 8;
        bf16x8 bh = *(const bf16x8*)(lds + KS_HI + boff);
        bf16x8 bl = *(const bf16x8*)(lds + KS_LO + boff);
        s = __builtin_amdgcn_mfma_f32_16x16x32_bf16(aqh[ks], bh, s, 0, 0, 0);
        s = __builtin_amdgcn_mfma_f32_16x16x32_bf16(aqh[ks], bl, s, 0, 0, 0);
        s = __builtin_amdgcn_mfma_f32_16x16x32_bf16(aql[ks], bh, s, 0, 0, 0);
      }
      S[e][j] = s;
    }
  }

  // ---- Phase B: mask + softmax (C layout: row=lq*4+rr, col=lm) ----
  const float NEG = -3.0e38f;
  float mx[4] = {NEG, NEG, NEG, NEG};
#pragma unroll
  for (int e = 0; e < 4; ++e)
#pragma unroll
    for (int j = 0; j < 3; ++j) {
      const int sl = j * 16 + lm;
#pragma unroll
      for (int rr = 0; rr < 4; ++rr) {
        const int m = lq * 4 + rr;
        const bool valid = ((unsigned)(sl - m) <= 31u);
        const float v = valid ? S[e][j][rr] * 0.125f : NEG;
        S[e][j][rr] = v;
        mx[rr] = fmaxf(mx[rr], v);
      }
    }
#pragma unroll
  for (int rr = 0; rr < 4; ++rr) {
    float m = mx[rr];
    m = fmaxf(m, __shfl_xor(m, 1));
    m = fmaxf(m, __shfl_xor(m, 2));
    m = fmaxf(m, __shfl_xor(m, 4));
    m = fmaxf(m, __shfl_xor(m, 8));
    mx[rr] = m;
  }
  float sm[4] = {0.f, 0.f, 0.f, 0.f};
#pragma unroll
  for (int e = 0; e < 4; ++e)
#pragma unroll
    for (int j = 0; j < 3; ++j)
#pragma unroll
      for (int rr = 0; rr < 4; ++rr) {
        const float p = __expf(S[e][j][rr] - mx[rr]);
        S[e][j][rr] = p;
        sm[rr] += p;
      }
  float inv[4];
#pragma unroll
  for (int rr = 0; rr < 4; ++rr) {
    float s = sm[rr];
    s += __shfl_xor(s, 1);
    s += __shfl_xor(s, 2);
    s += __shfl_xor(s, 4);
    s += __shfl_xor(s, 8);
    inv[rr] = 1.0f / s;
  }

  // ---- Phase C: PV, plain bf16 P (per-wave region, Vt read-only) ----
  f32x4 O[4] = {};
#pragma unroll
  for (int e = 0; e < 4; ++e) {
#pragma unroll
    for (int j = 0; j < 3; ++j)
#pragma unroll
      for (int rr = 0; rr < 4; ++rr)
        lds[PWH + (lq * 4 + rr) * 72 + j * 16 + lm] = f2bf(S[e][j][rr] * inv[rr]);
    bf16x8 ah[2];
#pragma unroll
    for (int ks = 0; ks < 2; ++ks)
      ah[ks] = *(const bf16x8*)(lds + PWH + lm * 72 + ks * 32 + lq * 8);
#pragma unroll
    for (int nt = 0; nt < 4; ++nt)
#pragma unroll
      for (int ks = 0; ks < 2; ++ks) {
        const int boff = (nt * 16 + lm) * 72 + ks * 32 + lq * 8;
        bf16x8 vh = *(const bf16x8*)(lds + VT_B + e * VT_SZ + boff);
        O[nt] = __builtin_amdgcn_mfma_f32_16x16x32_bf16(ah[ks], vh, O[nt], 0, 0, 0);
      }
  }

#pragma unroll
  for (int nt = 0; nt < 4; ++nt)
#pragma unroll
    for (int rr = 0; rr < 4; ++rr) {
      const int t = t0 + lq * 4 + rr;
      const size_t oi = ((size_t)(n * 2048 + t)) * 512 + w * 64 + nt * 16 + lm;
      Ybh[oi] = f2bf(O[nt][rr]);
    }
}

// ---------------- K4: output GEMM (plain bf16 MFMA, BK=64) ----------------
__global__ __launch_bounds__(256) void gemm_out(
    const unsigned short* __restrict__ Yh,
    const unsigned short* __restrict__ Wh,
    float* __restrict__ out)
{
  __shared__ __align__(16) unsigned short Ash[2 * 128 * 32];
  __shared__ __align__(16) unsigned short Bsh[2 * 128 * 32];
  const int tid  = threadIdx.x;
  const int lane = tid & 63;
  const int w    = tid >> 6;
  const int wr   = w >> 1, wc = w & 1;
  const int lm   = lane & 15, lq = lane >> 4;
  const int rb   = blockIdx.x * 128;
  const int cb   = blockIdx.y * 128;
  const int srow = lane >> 2;
  const int skc  = (lane & 3) * 8;

  f32x4 acc[4][4] = {};
  for (int k0 = 0; k0 < 512; k0 += 64) {
#pragma unroll
    for (int p = 0; p < 2; ++p)
#pragma unroll
      for (int c = 0; c < 2; ++c) {
        const int r0   = w * 32 + c * 16;
        const int ldso = (p * 128 + r0) * 32;
        GLDS(Yh + (size_t)(rb + r0 + srow) * 512 + k0 + p * 32 + skc, Ash + ldso);
        GLDS(Wh + (size_t)(cb + r0 + srow) * 512 + k0 + p * 32 + skc, Bsh + ldso);
      }
    __syncthreads();
#pragma unroll
    for (int ks = 0; ks < 2; ++ks) {
      bf16x8 ah[4], bh[4];
#pragma unroll
      for (int i = 0; i < 4; ++i)
        ah[i] = *(const bf16x8*)(Ash + (ks * 128 + wr * 64 + i * 16 + lm) * 32 + lq * 8);
#pragma unroll
      for (int j = 0; j < 4; ++j)
        bh[j] = *(const bf16x8*)(Bsh + (ks * 128 + wc * 64 + j * 16 + lm) * 32 + lq * 8);
#pragma unroll
      for (int i = 0; i < 4; ++i)
#pragma unroll
        for (int j = 0; j < 4; ++j)
          acc[i][j] = __builtin_amdgcn_mfma_f32_16x16x32_bf16(ah[i], bh[j], acc[i][j], 0, 0, 0);
    }
    __syncthreads();
  }
#pragma unroll
  for (int i = 0; i < 4; ++i)
#pragma unroll
    for (int j = 0; j < 4; ++j)
#pragma unroll
      for (int rr = 0; rr < 4; ++rr) {
        const int m = rb + wr * 64 + i * 16 + lq * 4 + rr;
        const int c = cb + wc * 64 + j * 16 + lm;
        out[(size_t)m * 1024 + c] = acc[i][j][rr];
      }
}

extern "C" void kernel_launch(void* const* d_in, const int* in_sizes, int n_in,
                              void* d_out, int out_size, void* d_ws, size_t ws_size,
                              hipStream_t stream) {
  const float* X     = (const float*)d_in[0];
  const float* wG    = (const float*)d_in[1];
  const float* bG    = (const float*)d_in[2];
  const float* wK    = (const float*)d_in[3];
  const float* wV    = (const float*)d_in[4];
  const float* wQ    = (const float*)d_in[5];
  const float* wO    = (const float*)d_in[6];
  const float* initK = (const float*)d_in[7];
  const float* initV = (const float*)d_in[8];
  float* out = (float*)d_out;

  // --- workspace layout (heavy lifetime aliasing) ---
  float* ws = (float*)d_ws;
  float* Kb = ws;                    // 2,097,152 f
  float* Vb = Kb + 2097152;          // 2,097,152 f
  float* Qb = Vb + 2097152;          // 2,097,152 f
  float* Gb = Qb + 2097152;          //   131,072 f
  unsigned short* Xh   = (unsigned short*)(Gb + 131072);  // 4,194,304 s
  unsigned short* Xl   = Xh + 4194304;                    // 4,194,304 s
  unsigned short* Wh   = Xl + 4194304;                    // 1,703,936 s
  unsigned short* Wl   = Wh + 1703936;                    // 1,703,936 s
  unsigned short* wOth = Wl + 1703936;                    //   524,288 s
  // aliases (lifetimes don't overlap):
  unsigned* P    = (unsigned*)Xh;       // X planes dead after gemm_proj
  unsigned* recK = P;                   // 1,064,960 u
  unsigned* recV = P + 1064960;         // 1,064,960 u
  unsigned* gK   = P + 2129920;         // 1,048,576 u
  unsigned* gV   = (unsigned*)Wh;       // 1,048,576 u (W planes dead after gemm_proj)
  float*   Afac  = (float*)(gV + 1048576);  // 16,384 f (inside Wh+Wl region)
  unsigned short* Ybh = (unsigned short*)Kb;  // Kb dead after gate_combine

  cvt_all<<<dim3(6272), dim3(256), 0, stream>>>(X, wK, wV, wQ, wG, wO,
                                                Xh, Xl, Wh, Wl, wOth);
  gemm_proj<<<dim3(32, 13), dim3(256), 0, stream>>>(Xh, Xl, Wh, Wl, bG, Kb, Vb, Qb, Gb);
  gate_combine<<<dim3(256), dim3(256), 0, stream>>>(Gb, Kb, Vb, Afac, gK, gV);
  scan2<<<dim3(8, 32, 2), dim3(64), 0, stream>>>(Afac, gK, gV, initK, initV, recK, recV);
  attn_kernel<<<dim3(256), dim3(512), 0, stream>>>(Qb, recK, recV, Ybh);
  gemm_out<<<dim3(32, 8), dim3(256), 0, stream>>>(Ybh, wOth, out);
}